// Round 1
// baseline (216.787 us; speedup 1.0000x reference)
//
#include <hip/hip_runtime.h>
#include <math.h>

#define HH 512
#define WW 1024
#define NPIX (HH * WW)
#define KK 15
#define GAMMA 0.1f
#define MULTIPLIER 1.0f

// d_ws layout: [0..255]: float accumulator (acc[0]) ; [256 ...]: 2*float4 per pixel:
//   pk[2*i+0] = (px, py, pz, pn)   pk[2*i+1] = (nx, ny, nz, 0)

__global__ __launch_bounds__(256) void prep_kernel(
    const float* __restrict__ sig1,
    const float* __restrict__ sig2,
    float4* __restrict__ pk,
    float* __restrict__ acc) {
  int i = blockIdx.x * 256 + threadIdx.x;
  if (i == 0) acc[0] = 0.0f;
  if (i >= NPIX) return;

  int h = i >> 10;           // i / W, W = 1024
  int w = i & (WW - 1);      // i % W
  const float PI = 3.14159265358979323846f;
  float lat = (0.5f - (h + 0.5f) * (1.0f / HH)) * PI;
  float lon = ((w + 0.5f) * (1.0f / WW) - 0.5f) * (2.0f * PI);
  float sla, cla, slo, clo;
  sincosf(lat, &sla, &cla);
  sincosf(lon, &slo, &clo);
  float dx = cla * slo;      // x = cos(lat) * sin(lon)
  float dy = sla;            // y = sin(lat)
  float dz = cla * clo;      // z = cos(lat) * cos(lon)

  float s = sig1[i];
  float nx = sig2[i];
  float ny = sig2[NPIX + i];
  float nz = sig2[2 * NPIX + i];

  float px = s * dx, py = s * dy, pz = s * dz;
  float pn = px * nx + py * ny + pz * nz;

  pk[2 * i + 0] = make_float4(px, py, pz, pn);
  pk[2 * i + 1] = make_float4(nx, ny, nz, 0.0f);
}

__global__ __launch_bounds__(256) void main_kernel(
    const float4* __restrict__ pk,
    const float* __restrict__ weights,
    const int* __restrict__ nb,
    float* __restrict__ acc) {
  int i = blockIdx.x * 256 + threadIdx.x;
  float local = 0.0f;

  if (i < NPIX) {
    float4 a = pk[2 * i + 0];   // px,py,pz,pn of center
    float4 b = pk[2 * i + 1];   // nx,ny,nz of center
    float pn = a.w;
    float nx = b.x, ny = b.y, nz = b.z;

    float sq = 0.0f, t2 = 0.0f;
#pragma unroll
    for (int k = 0; k < KK; ++k) {
      int j = nb[k * NPIX + i];
      float wgt = weights[k * NPIX + i];
      float4 pj = pk[2 * j + 0];
      float4 nj = pk[2 * j + 1];
      // aux1 = pn_i - dot(p_j, n_i)
      float aux1 = pn - (pj.x * nx + pj.y * ny + pj.z * nz);
      // aux2 = || n_i - n_j ||
      float ddx = nx - nj.x, ddy = ny - nj.y, ddz = nz - nj.z;
      float aux2 = sqrtf(ddx * ddx + ddy * ddy + ddz * ddz);
      float aw = aux1 * wgt;
      sq += aw * aw;
      t2 += aux2 * wgt;
    }
    local = sqrtf(sq) + GAMMA * t2;
  }

  // wave (64-lane) shuffle reduction
  for (int off = 32; off > 0; off >>= 1)
    local += __shfl_down(local, off, 64);

  __shared__ float smem[4];
  int lane = threadIdx.x & 63;
  int wid = threadIdx.x >> 6;
  if (lane == 0) smem[wid] = local;
  __syncthreads();
  if (threadIdx.x == 0) {
    float s = smem[0] + smem[1] + smem[2] + smem[3];
    atomicAdd(acc, s);
  }
}

__global__ void fin_kernel(const float* __restrict__ acc, float* __restrict__ out) {
  if (threadIdx.x == 0 && blockIdx.x == 0)
    out[0] = MULTIPLIER * acc[0] * (1.0f / (float)NPIX);
}

extern "C" void kernel_launch(void* const* d_in, const int* in_sizes, int n_in,
                              void* d_out, int out_size, void* d_ws, size_t ws_size,
                              hipStream_t stream) {
  const float* sig1 = (const float*)d_in[0];
  const float* sig2 = (const float*)d_in[1];
  const float* wts  = (const float*)d_in[2];
  const int*   nb   = (const int*)d_in[3];
  float* out = (float*)d_out;

  float*  acc = (float*)d_ws;
  float4* pk  = (float4*)((char*)d_ws + 256);

  int blocks = NPIX / 256;  // 2048
  hipLaunchKernelGGL(prep_kernel, dim3(blocks), dim3(256), 0, stream, sig1, sig2, pk, acc);
  hipLaunchKernelGGL(main_kernel, dim3(blocks), dim3(256), 0, stream, pk, wts, nb, acc);
  hipLaunchKernelGGL(fin_kernel, dim3(1), dim3(64), 0, stream, acc, out);
}

// Round 2
// 174.490 us; speedup vs baseline: 1.2424x; 1.2424x over previous
//
#include <hip/hip_runtime.h>
#include <hip/hip_fp16.h>
#include <math.h>

#define HH 512
#define WW 1024
#define NPIX (HH * WW)
#define KK 15
#define GAMMA 0.1f
#define MULTIPLIER 1.0f

// d_ws layout: [0..255]: float accumulator acc[0]; then uint4 pack[NPIX] (16 B/pixel):
//   pack.x = half2(px, py)
//   pack.y = half2(pz, nx)
//   pack.z = half2(ny, nz)
//   pack.w = bits of fp32 pn = dot(p, n)

__device__ inline unsigned int pack2f(float a, float b) {
  __half2 h = __floats2half2_rn(a, b);
  return *(unsigned int*)&h;
}
__device__ inline float2 up2(unsigned int u) {
  __half2 h = *(__half2*)&u;
  return __half22float2(h);
}

__global__ __launch_bounds__(256) void prep_kernel(
    const float* __restrict__ sig1,
    const float* __restrict__ sig2,
    uint4* __restrict__ pack,
    float* __restrict__ acc) {
  int i = blockIdx.x * 256 + threadIdx.x;
  if (i == 0) acc[0] = 0.0f;

  int h = i >> 10;           // i / W
  int w = i & (WW - 1);      // i % W
  const float PI = 3.14159265358979323846f;
  float lat = (0.5f - (h + 0.5f) * (1.0f / HH)) * PI;
  float lon = ((w + 0.5f) * (1.0f / WW) - 0.5f) * (2.0f * PI);
  float sla = __sinf(lat), cla = __cosf(lat);
  float slo = __sinf(lon), clo = __cosf(lon);
  float dx = cla * slo;
  float dy = sla;
  float dz = cla * clo;

  float s = sig1[i];
  float nx = sig2[i];
  float ny = sig2[NPIX + i];
  float nz = sig2[2 * NPIX + i];

  float px = s * dx, py = s * dy, pz = s * dz;
  float pn = px * nx + py * ny + pz * nz;

  uint4 u;
  u.x = pack2f(px, py);
  u.y = pack2f(pz, nx);
  u.z = pack2f(ny, nz);
  u.w = __float_as_uint(pn);
  pack[i] = u;
}

__global__ __launch_bounds__(256) void main_kernel(
    const uint4* __restrict__ pack,
    const float* __restrict__ weights,
    const int* __restrict__ nb,
    float* __restrict__ acc) {
  int i = blockIdx.x * 256 + threadIdx.x;   // grid covers NPIX exactly

  // 1) all neighbour indices (streaming, coalesced)
  int j[KK];
#pragma unroll
  for (int k = 0; k < KK; ++k) j[k] = nb[k * NPIX + i];

  // 2) issue ALL gathers before consuming any -> 15 loads in flight
  uint4 g[KK];
#pragma unroll
  for (int k = 0; k < KK; ++k) g[k] = pack[j[k]];

  // 3) weights stream (hides under gather latency)
  float wv[KK];
#pragma unroll
  for (int k = 0; k < KK; ++k) wv[k] = weights[k * NPIX + i];

  // 4) center values
  uint4 c = pack[i];
  float2 cy = up2(c.y), cz = up2(c.z);
  float nix = cy.y, niy = cz.x, niz = cz.y;
  float pn = __uint_as_float(c.w);

  float sq = 0.0f, t2 = 0.0f;
#pragma unroll
  for (int k = 0; k < KK; ++k) {
    float2 gx = up2(g[k].x);   // pjx, pjy
    float2 gy = up2(g[k].y);   // pjz, njx
    float2 gz = up2(g[k].z);   // njy, njz
    float aux1 = pn - (gx.x * nix + gx.y * niy + gy.x * niz);
    float ddx = nix - gy.y, ddy = niy - gz.x, ddz = niz - gz.y;
    float aux2 = sqrtf(ddx * ddx + ddy * ddy + ddz * ddz);
    float aw = aux1 * wv[k];
    sq += aw * aw;
    t2 += aux2 * wv[k];
  }
  float local = sqrtf(sq) + GAMMA * t2;

  // wave (64-lane) reduction
  for (int off = 32; off > 0; off >>= 1)
    local += __shfl_down(local, off, 64);

  __shared__ float smem[4];
  int lane = threadIdx.x & 63;
  int wid = threadIdx.x >> 6;
  if (lane == 0) smem[wid] = local;
  __syncthreads();
  if (threadIdx.x == 0) {
    float s = smem[0] + smem[1] + smem[2] + smem[3];
    atomicAdd(acc, s);
  }
}

__global__ void fin_kernel(const float* __restrict__ acc, float* __restrict__ out) {
  if (threadIdx.x == 0 && blockIdx.x == 0)
    out[0] = MULTIPLIER * acc[0] * (1.0f / (float)NPIX);
}

extern "C" void kernel_launch(void* const* d_in, const int* in_sizes, int n_in,
                              void* d_out, int out_size, void* d_ws, size_t ws_size,
                              hipStream_t stream) {
  const float* sig1 = (const float*)d_in[0];
  const float* sig2 = (const float*)d_in[1];
  const float* wts  = (const float*)d_in[2];
  const int*   nb   = (const int*)d_in[3];
  float* out = (float*)d_out;

  float* acc = (float*)d_ws;
  uint4* pack = (uint4*)((char*)d_ws + 256);

  int blocks = NPIX / 256;  // 2048
  hipLaunchKernelGGL(prep_kernel, dim3(blocks), dim3(256), 0, stream, sig1, sig2, pack, acc);
  hipLaunchKernelGGL(main_kernel, dim3(blocks), dim3(256), 0, stream, pack, wts, nb, acc);
  hipLaunchKernelGGL(fin_kernel, dim3(1), dim3(64), 0, stream, acc, out);
}